// Round 6
// baseline (73.411 us; speedup 1.0000x reference)
//
#include <hip/hip_runtime.h>
#include <math.h>

// R6: single-dispatch, single-block. Early exit is exact by monotonicity:
// fp32 addition of non-negatives is monotone, so a wave exiting because a
// lane's running sum >= 2000 publishes a wave partial >= 2000 => the pair's
// total fails the `pen < 2000` keep-test — identical discard to the
// reference. Per-PAIR LDS hint (advisory, CU-local) bounds the tail; no
// device globals, no atomics, no second dispatch.

namespace {
constexpr int kNV = 6890;
constexpr int kNF = 13776;
constexpr int kP  = 8;                          // person-pairs
constexpr int kC  = 65536;                      // collisions per pair
constexpr int kTPB = 1024;                      // 16 waves: 2 per pair
constexpr int kLanesPerPair = 128;              // 2 waves * 64 lanes
constexpr int kPasses = kC / kLanesPerPair;     // 512 (worst case; ~1-2 typical)
}

#define SIGMA_F  1e-4f
#define EPS_F    1e-9f
#define THRESH_F 2000.0f
#define WEIGHT_F 0.1f

// Exact reference-order cone distance field for one (receiver, intruder) pair.
__device__ __forceinline__ float cone_pair_loss(
    float3 r0, float3 r1, float3 r2, float3 i0, float3 i1, float3 i2) {
    float e1x = r1.x - r0.x, e1y = r1.y - r0.y, e1z = r1.z - r0.z;
    float e2x = r2.x - r0.x, e2y = r2.y - r0.y, e2z = r2.z - r0.z;
    float nx = e1y * e2z - e1z * e2y;
    float ny = e1z * e2x - e1x * e2z;
    float nz = e1x * e2y - e1y * e2x;
    float nn = sqrtf(nx * nx + ny * ny + nz * nz) + EPS_F;
    nx /= nn; ny /= nn; nz /= nn;
    float cx = (r0.x + r1.x + r2.x) / 3.0f;
    float cy = (r0.y + r1.y + r2.y) / 3.0f;
    float cz = (r0.z + r1.z + r2.z) / 3.0f;
    float r2m = 0.0f;
    {
        float dx = r0.x - cx, dy = r0.y - cy, dz = r0.z - cz;
        r2m = fmaxf(r2m, dx * dx + dy * dy + dz * dz);
        dx = r1.x - cx; dy = r1.y - cy; dz = r1.z - cz;
        r2m = fmaxf(r2m, dx * dx + dy * dy + dz * dz);
        dx = r2.x - cx; dy = r2.y - cy; dz = r2.z - cz;
        r2m = fmaxf(r2m, dx * dx + dy * dy + dz * dz);
    }
    float rad_eps = sqrtf(r2m) + EPS_F;
    float3 iv[3] = {i0, i1, i2};
    float acc = 0.0f;
#pragma unroll
    for (int k = 0; k < 3; ++k) {
        float dx = iv[k].x - cx, dy = iv[k].y - cy, dz = iv[k].z - cz;
        float d = dx * nx + dy * ny + dz * nz;
        float px = dx - d * nx, py = dy - d * ny, pz = dz - d * nz;
        float radial = sqrtf(px * px + py * py + pz * pz);
        float fa = fmaxf(-d / SIGMA_F, 0.0f);
        float fb = fmaxf(1.0f - radial / rad_eps, 0.0f);
        float fd = fa * fb;
        acc += fd * fd;
    }
    return acc;
}

// Direct gather + eval of one collision (branchless validity multiply so all
// scattered loads issue back-to-back).
__device__ __forceinline__ float eval_collision(
    int p, int2 idx,
    const float* __restrict__ verts, const int* __restrict__ faces,
    float t0x, float t0y, float t0z, float t1x, float t1y, float t1z) {
    int hi = (idx.x >= kNF) ? 1 : 0;
    int hr = (idx.y >= kNF) ? 1 : 0;
    const int* fi = faces + 3 * (idx.x - hi * kNF);
    const int* fr = faces + 3 * (idx.y - hr * kNF);
    int vi0 = fi[0], vi1 = fi[1], vi2 = fi[2];
    int vr0 = fr[0], vr1 = fr[1], vr2 = fr[2];
    size_t bi = (size_t)(2 * p + hi) * kNV;
    size_t br = (size_t)(2 * p + hr) * kNV;
    float tix = hi ? t1x : t0x, tiy = hi ? t1y : t0y, tiz = hi ? t1z : t0z;
    float trx = hr ? t1x : t0x, try_ = hr ? t1y : t0y, trz = hr ? t1z : t0z;
    const float* q;
    q = verts + (bi + vi0) * 3; float3 i0 = make_float3(q[0] + tix, q[1] + tiy, q[2] + tiz);
    q = verts + (bi + vi1) * 3; float3 i1 = make_float3(q[0] + tix, q[1] + tiy, q[2] + tiz);
    q = verts + (bi + vi2) * 3; float3 i2 = make_float3(q[0] + tix, q[1] + tiy, q[2] + tiz);
    q = verts + (br + vr0) * 3; float3 r0 = make_float3(q[0] + trx, q[1] + try_, q[2] + trz);
    q = verts + (br + vr1) * 3; float3 r1 = make_float3(q[0] + trx, q[1] + try_, q[2] + trz);
    q = verts + (br + vr2) * 3; float3 r2 = make_float3(q[0] + trx, q[1] + try_, q[2] + trz);
    float v = cone_pair_loss(r0, r1, r2, i0, i1, i2);
    return (idx.x != idx.y) ? v : 0.0f;
}

// One block, 16 waves; waves 2p and 2p+1 own pair p (128 collisions/pass).
// Wave-local exact early exit; per-pair advisory LDS hint (benign race: a
// hinted wave's truncated partial only ever affects a pair already proven
// >= 2000). Inline finalize after one barrier.
__global__ void __launch_bounds__(1024)
pen_single(const int* __restrict__ coll,
           const float* __restrict__ verts,
           const float* __restrict__ trans,
           const int* __restrict__ faces,
           float* __restrict__ out) {
    const int tid  = threadIdx.x;
    const int lane = tid & 63;
    const int w    = tid >> 6;        // wave 0..15
    const int p    = w >> 1;          // pair 0..7
    const int sub  = w & 1;           // which half of the pair's lanes
    const int2* cp = (const int2*)coll + (size_t)p * kC;

    const float t0x = trans[6 * p + 0], t0y = trans[6 * p + 1], t0z = trans[6 * p + 2];
    const float t1x = trans[6 * p + 3], t1y = trans[6 * p + 4], t1z = trans[6 * p + 5];

    __shared__ int   s_exit[kP];
    __shared__ float s_red[16];
    if (tid < kP) s_exit[tid] = 0;
    __syncthreads();
    volatile int* vexit = s_exit;

    float acc = 0.0f;
    for (int s = 0; s < kPasses; ++s) {
        int2 idx = cp[s * kLanesPerPair + sub * 64 + lane];
        acc += eval_collision(p, idx, verts, faces, t0x, t0y, t0z, t1x, t1y, t1z);
        if (__any(acc >= THRESH_F)) {     // wave partial now >= 2000: exact proof
            if (lane == 0) vexit[p] = 1;  // per-pair CU-local hint
            break;
        }
        if (vexit[p]) break;              // advisory; only fires on proven pairs
    }

    // wave partial -> LDS
#pragma unroll
    for (int off = 32; off > 0; off >>= 1)
        acc += __shfl_down(acc, off, 64);
    if (lane == 0) s_red[w] = acc;
    __syncthreads();

    if (tid == 0) {
        float cnt = 0.0f, vals = 0.0f;
#pragma unroll
        for (int e = 0; e < kP; ++e) {
            float pq = s_red[2 * e] + s_red[2 * e + 1];
            if (pq < THRESH_F) {          // NaN pen => excluded, matches jax
                cnt += 1.0f;
                vals += 1.0f / (1.0f + expf(-pq / THRESH_F)) - 0.5f;
            }
        }
        float loss = (cnt > 0.0f) ? (vals / fmaxf(cnt, 1.0f)) : 0.0f;
        out[0] = loss * WEIGHT_F;
    }
}

extern "C" void kernel_launch(void* const* d_in, const int* in_sizes, int n_in,
                              void* d_out, int out_size, void* d_ws, size_t ws_size,
                              hipStream_t stream) {
    const float* verts = (const float*)d_in[0];
    const float* trans = (const float*)d_in[1];
    const int*   faces = (const int*)d_in[2];
    const int*   coll  = (const int*)d_in[3];
    (void)d_ws; (void)ws_size; (void)in_sizes; (void)n_in; (void)out_size;
    pen_single<<<1, kTPB, 0, stream>>>(coll, verts, trans, faces, (float*)d_out);
}

// Round 7
// 68.563 us; speedup vs baseline: 1.0707x; 1.0707x over previous
//
#include <hip/hip_runtime.h>
#include <math.h>

// R7: R5's proven 256-block shape (65.2us) + in-kernel finalize.
// - Early exit is exact by monotonicity: fp32 addition of non-negatives is
//   monotone (a+b >= max(a,b)), so a wave exiting because a lane's running
//   sum >= 2000 publishes a wave partial >= 2000 => the pair total fails the
//   `pen < 2000` keep-test in ANY summation order — identical discard to ref.
// - Completion uses per-block release-flag stores (256 distinct addresses,
//   zero RMW atomics => none of R2's same-line coherence serialization).
//   Block 0 acquire-polls the flags; blocks 1..255 depend on nothing, so
//   forward progress is unconditional (no deadlock at any residency).
// - coll-index prefetch takes the top of the dependent load chain off the
//   per-pass critical path.

namespace {
constexpr int kNV = 6890;
constexpr int kNF = 13776;
constexpr int kP  = 8;                            // person-pairs
constexpr int kC  = 65536;                        // collisions per pair
constexpr int kNB = 256;                          // blocks (p = blk & 7 -> XCD-pinned)
constexpr int kTPB = 256;                         // 4 waves / block
constexpr int kWPB = kTPB / 64;
constexpr int kBlocksPerPair = kNB / kP;          // 32
constexpr int kPasses = kC / (kBlocksPerPair * kTPB);  // 8
}

#define SIGMA_F  1e-4f
#define EPS_F    1e-9f
#define THRESH_F 2000.0f
#define WEIGHT_F 0.1f

// g_partials[blk]: plain store, published by g_done[blk] release flag.
// g_done: set to 1 by block blk (release), consumed + reset to 0 by block 0
// (acquire then relaxed store) => self-resetting across graph replays.
__device__ float g_partials[kNB];
__device__ int   g_done[kNB] = {};

// Exact reference-order cone distance field for one (receiver, intruder) pair.
__device__ __forceinline__ float cone_pair_loss(
    float3 r0, float3 r1, float3 r2, float3 i0, float3 i1, float3 i2) {
    float e1x = r1.x - r0.x, e1y = r1.y - r0.y, e1z = r1.z - r0.z;
    float e2x = r2.x - r0.x, e2y = r2.y - r0.y, e2z = r2.z - r0.z;
    float nx = e1y * e2z - e1z * e2y;
    float ny = e1z * e2x - e1x * e2z;
    float nz = e1x * e2y - e1y * e2x;
    float nn = sqrtf(nx * nx + ny * ny + nz * nz) + EPS_F;
    nx /= nn; ny /= nn; nz /= nn;
    float cx = (r0.x + r1.x + r2.x) / 3.0f;
    float cy = (r0.y + r1.y + r2.y) / 3.0f;
    float cz = (r0.z + r1.z + r2.z) / 3.0f;
    float r2m = 0.0f;
    {
        float dx = r0.x - cx, dy = r0.y - cy, dz = r0.z - cz;
        r2m = fmaxf(r2m, dx * dx + dy * dy + dz * dz);
        dx = r1.x - cx; dy = r1.y - cy; dz = r1.z - cz;
        r2m = fmaxf(r2m, dx * dx + dy * dy + dz * dz);
        dx = r2.x - cx; dy = r2.y - cy; dz = r2.z - cz;
        r2m = fmaxf(r2m, dx * dx + dy * dy + dz * dz);
    }
    float rad_eps = sqrtf(r2m) + EPS_F;
    float3 iv[3] = {i0, i1, i2};
    float acc = 0.0f;
#pragma unroll
    for (int k = 0; k < 3; ++k) {
        float dx = iv[k].x - cx, dy = iv[k].y - cy, dz = iv[k].z - cz;
        float d = dx * nx + dy * ny + dz * nz;
        float px = dx - d * nx, py = dy - d * ny, pz = dz - d * nz;
        float radial = sqrtf(px * px + py * py + pz * pz);
        float fa = fmaxf(-d / SIGMA_F, 0.0f);
        float fb = fmaxf(1.0f - radial / rad_eps, 0.0f);
        float fd = fa * fb;
        acc += fd * fd;
    }
    return acc;
}

// Direct gather + eval of one collision (branchless validity multiply so all
// scattered loads issue back-to-back).
__device__ __forceinline__ float eval_collision(
    int p, int2 idx,
    const float* __restrict__ verts, const int* __restrict__ faces,
    float t0x, float t0y, float t0z, float t1x, float t1y, float t1z) {
    int hi = (idx.x >= kNF) ? 1 : 0;
    int hr = (idx.y >= kNF) ? 1 : 0;
    const int* fi = faces + 3 * (idx.x - hi * kNF);
    const int* fr = faces + 3 * (idx.y - hr * kNF);
    int vi0 = fi[0], vi1 = fi[1], vi2 = fi[2];
    int vr0 = fr[0], vr1 = fr[1], vr2 = fr[2];
    size_t bi = (size_t)(2 * p + hi) * kNV;
    size_t br = (size_t)(2 * p + hr) * kNV;
    float tix = hi ? t1x : t0x, tiy = hi ? t1y : t0y, tiz = hi ? t1z : t0z;
    float trx = hr ? t1x : t0x, try_ = hr ? t1y : t0y, trz = hr ? t1z : t0z;
    const float* q;
    q = verts + (bi + vi0) * 3; float3 i0 = make_float3(q[0] + tix, q[1] + tiy, q[2] + tiz);
    q = verts + (bi + vi1) * 3; float3 i1 = make_float3(q[0] + tix, q[1] + tiy, q[2] + tiz);
    q = verts + (bi + vi2) * 3; float3 i2 = make_float3(q[0] + tix, q[1] + tiy, q[2] + tiz);
    q = verts + (br + vr0) * 3; float3 r0 = make_float3(q[0] + trx, q[1] + try_, q[2] + trz);
    q = verts + (br + vr1) * 3; float3 r1 = make_float3(q[0] + trx, q[1] + try_, q[2] + trz);
    q = verts + (br + vr2) * 3; float3 r2 = make_float3(q[0] + trx, q[1] + try_, q[2] + trz);
    float v = cone_pair_loss(r0, r1, r2, i0, i1, i2);
    return (idx.x != idx.y) ? v : 0.0f;
}

__global__ void __launch_bounds__(256)
pen_kernel(const int* __restrict__ coll,
           const float* __restrict__ verts,
           const float* __restrict__ trans,
           const int* __restrict__ faces,
           float* __restrict__ out) {
    const int blk  = blockIdx.x;
    const int p    = blk & 7;                          // XCD-pinned pair
    const int tid  = threadIdx.x;
    const int lane = tid & 63;
    const int wid  = tid >> 6;
    const int2* cp = (const int2*)coll + (size_t)p * kC
                   + (size_t)(blk >> 3) * (kPasses * kTPB);

    const float t0x = trans[6 * p + 0], t0y = trans[6 * p + 1], t0z = trans[6 * p + 2];
    const float t1x = trans[6 * p + 3], t1y = trans[6 * p + 4], t1z = trans[6 * p + 5];

    volatile __shared__ int s_exit;
    if (tid == 0) s_exit = 0;
    __syncthreads();

    float acc = 0.0f;
    int2 idx = cp[tid];                          // prefetch pass 0
    for (int s = 0; s < kPasses; ++s) {
        int2 cur = idx;
        if (s + 1 < kPasses)
            idx = cp[(s + 1) * kTPB + tid];      // prefetch next pass
        acc += eval_collision(p, cur, verts, faces, t0x, t0y, t0z, t1x, t1y, t1z);
        if (__any(acc >= THRESH_F)) {
            // this wave's partial is already >= 2000 => pair provably discarded
            if (lane == 0) s_exit = 1;           // CU-local hint for sibling waves
            break;
        }
        if (s + 1 < kPasses && s_exit) break;    // advisory; benign race
    }

    // wave reduce -> LDS -> one plain store + release flag per block
#pragma unroll
    for (int off = 32; off > 0; off >>= 1)
        acc += __shfl_down(acc, off, 64);
    __shared__ float red[kWPB];
    if (lane == 0) red[wid] = acc;
    __syncthreads();
    if (tid == 0) {
        g_partials[blk] = red[0] + red[1] + red[2] + red[3];
        __hip_atomic_store(&g_done[blk], 1, __ATOMIC_RELEASE,
                           __HIP_MEMORY_SCOPE_AGENT);
    }
    if (blk != 0) return;

    // ---- block 0: in-kernel finalize ----
    // thread i consumes block i's flag; release->acquire on g_done[i] makes
    // g_partials[i] visible. Blocks 1..255 never wait on anything => they
    // always retire and set their flags; this poll terminates unconditionally.
    while (__hip_atomic_load(&g_done[tid], __ATOMIC_ACQUIRE,
                             __HIP_MEMORY_SCOPE_AGENT) == 0)
        __builtin_amdgcn_s_sleep(2);
    __hip_atomic_store(&g_done[tid], 0, __ATOMIC_RELAXED,
                       __HIP_MEMORY_SCOPE_AGENT);          // reset for next replay
    float v = g_partials[tid];                              // pair (tid & 7)

    // per-pair reduce: fold lanes 8 apart => lanes 0..7 hold this wave's
    // per-pair sums over its 64-block slice.
#pragma unroll
    for (int off = 32; off >= 8; off >>= 1)
        v += __shfl_down(v, off, 64);
    __shared__ float s_p[kWPB][kP];
    if (lane < kP) s_p[wid][lane] = v;
    __syncthreads();
    if (tid == 0) {
        float cnt = 0.0f, vals = 0.0f;
#pragma unroll
        for (int e = 0; e < kP; ++e) {
            float pq = s_p[0][e] + s_p[1][e] + s_p[2][e] + s_p[3][e];
            if (pq < THRESH_F) {          // NaN pen => excluded, matches jax
                cnt += 1.0f;
                vals += 1.0f / (1.0f + expf(-pq / THRESH_F)) - 0.5f;
            }
        }
        float loss = (cnt > 0.0f) ? (vals / fmaxf(cnt, 1.0f)) : 0.0f;
        out[0] = loss * WEIGHT_F;
    }
}

extern "C" void kernel_launch(void* const* d_in, const int* in_sizes, int n_in,
                              void* d_out, int out_size, void* d_ws, size_t ws_size,
                              hipStream_t stream) {
    const float* verts = (const float*)d_in[0];
    const float* trans = (const float*)d_in[1];
    const int*   faces = (const int*)d_in[2];
    const int*   coll  = (const int*)d_in[3];
    (void)d_ws; (void)ws_size; (void)in_sizes; (void)n_in; (void)out_size;
    pen_kernel<<<kNB, kTPB, 0, stream>>>(coll, verts, trans, faces, (float*)d_out);
}

// Round 8
// 66.547 us; speedup vs baseline: 1.1031x; 1.0303x over previous
//
#include <hip/hip_runtime.h>
#include <math.h>

// R8 = byte-level revert to R5 (best measured: 65.2us). R6 (single-block,
// 73.4) and R7 (in-kernel finalize, 68.6) both regressed vs this structure.
//
// Zero-communication early exit. Key invariant: fp32 addition of
// non-negatives is monotone, so a wave that exits because some lane's running
// sum >= 2000 necessarily publishes a wave partial >= 2000; the pair's summed
// partials then fail finalize's `pen < 2000` keep-test — the same exact
// discard the reference computes. No flags, no atomics, no RMWs anywhere.

namespace {
constexpr int kNV = 6890;
constexpr int kNF = 13776;
constexpr int kP  = 8;                            // person-pairs
constexpr int kC  = 65536;                        // collisions per pair
constexpr int kNB = 256;                          // blocks (p = blk & 7 -> XCD-pinned)
constexpr int kTPB = 256;                         // 4 waves / block
constexpr int kWPB = kTPB / 64;
constexpr int kBlocksPerPair = kNB / kP;          // 32
constexpr int kPasses = kC / (kBlocksPerPair * kTPB);  // 8
}

#define SIGMA_F  1e-4f
#define EPS_F    1e-9f
#define THRESH_F 2000.0f
#define WEIGHT_F 0.1f

// One slot per block; unconditionally overwritten every replay before being
// read => needs no reset. Plain stores only; cross-dispatch visibility is
// guaranteed by same-stream kernel ordering.
__device__ float g_partials[kNB];

// Exact reference-order cone distance field for one (receiver, intruder) pair.
__device__ __forceinline__ float cone_pair_loss(
    float3 r0, float3 r1, float3 r2, float3 i0, float3 i1, float3 i2) {
    float e1x = r1.x - r0.x, e1y = r1.y - r0.y, e1z = r1.z - r0.z;
    float e2x = r2.x - r0.x, e2y = r2.y - r0.y, e2z = r2.z - r0.z;
    float nx = e1y * e2z - e1z * e2y;
    float ny = e1z * e2x - e1x * e2z;
    float nz = e1x * e2y - e1y * e2x;
    float nn = sqrtf(nx * nx + ny * ny + nz * nz) + EPS_F;
    nx /= nn; ny /= nn; nz /= nn;
    float cx = (r0.x + r1.x + r2.x) / 3.0f;
    float cy = (r0.y + r1.y + r2.y) / 3.0f;
    float cz = (r0.z + r1.z + r2.z) / 3.0f;
    float r2m = 0.0f;
    {
        float dx = r0.x - cx, dy = r0.y - cy, dz = r0.z - cz;
        r2m = fmaxf(r2m, dx * dx + dy * dy + dz * dz);
        dx = r1.x - cx; dy = r1.y - cy; dz = r1.z - cz;
        r2m = fmaxf(r2m, dx * dx + dy * dy + dz * dz);
        dx = r2.x - cx; dy = r2.y - cy; dz = r2.z - cz;
        r2m = fmaxf(r2m, dx * dx + dy * dy + dz * dz);
    }
    float rad_eps = sqrtf(r2m) + EPS_F;
    float3 iv[3] = {i0, i1, i2};
    float acc = 0.0f;
#pragma unroll
    for (int k = 0; k < 3; ++k) {
        float dx = iv[k].x - cx, dy = iv[k].y - cy, dz = iv[k].z - cz;
        float d = dx * nx + dy * ny + dz * nz;
        float px = dx - d * nx, py = dy - d * ny, pz = dz - d * nz;
        float radial = sqrtf(px * px + py * py + pz * pz);
        float fa = fmaxf(-d / SIGMA_F, 0.0f);
        float fb = fmaxf(1.0f - radial / rad_eps, 0.0f);
        float fd = fa * fb;
        acc += fd * fd;
    }
    return acc;
}

// Direct gather + eval of one collision (branchless validity multiply so all
// scattered loads issue back-to-back).
__device__ __forceinline__ float eval_collision(
    int p, int2 idx,
    const float* __restrict__ verts, const int* __restrict__ faces,
    float t0x, float t0y, float t0z, float t1x, float t1y, float t1z) {
    int hi = (idx.x >= kNF) ? 1 : 0;
    int hr = (idx.y >= kNF) ? 1 : 0;
    const int* fi = faces + 3 * (idx.x - hi * kNF);
    const int* fr = faces + 3 * (idx.y - hr * kNF);
    int vi0 = fi[0], vi1 = fi[1], vi2 = fi[2];
    int vr0 = fr[0], vr1 = fr[1], vr2 = fr[2];
    size_t bi = (size_t)(2 * p + hi) * kNV;
    size_t br = (size_t)(2 * p + hr) * kNV;
    float tix = hi ? t1x : t0x, tiy = hi ? t1y : t0y, tiz = hi ? t1z : t0z;
    float trx = hr ? t1x : t0x, try_ = hr ? t1y : t0y, trz = hr ? t1z : t0z;
    const float* q;
    q = verts + (bi + vi0) * 3; float3 i0 = make_float3(q[0] + tix, q[1] + tiy, q[2] + tiz);
    q = verts + (bi + vi1) * 3; float3 i1 = make_float3(q[0] + tix, q[1] + tiy, q[2] + tiz);
    q = verts + (bi + vi2) * 3; float3 i2 = make_float3(q[0] + tix, q[1] + tiy, q[2] + tiz);
    q = verts + (br + vr0) * 3; float3 r0 = make_float3(q[0] + trx, q[1] + try_, q[2] + trz);
    q = verts + (br + vr1) * 3; float3 r1 = make_float3(q[0] + trx, q[1] + try_, q[2] + trz);
    q = verts + (br + vr2) * 3; float3 r2 = make_float3(q[0] + trx, q[1] + try_, q[2] + trz);
    float v = cone_pair_loss(r0, r1, r2, i0, i1, i2);
    return (idx.x != idx.y) ? v : 0.0f;
}

// Pass loop: wave-local exact early exit (ballot only). Block-local advisory
// hint via volatile LDS (CU-local, no coherence traffic) bounds the tail for
// waves that never self-trigger. No global communication of any kind.
__global__ void __launch_bounds__(256)
pen_kernel(const int* __restrict__ coll,
           const float* __restrict__ verts,
           const float* __restrict__ trans,
           const int* __restrict__ faces) {
    const int blk  = blockIdx.x;
    const int p    = blk & 7;                          // XCD-pinned pair
    const int lane = threadIdx.x & 63;
    const int wid  = threadIdx.x >> 6;
    const int2* cp = (const int2*)coll + (size_t)p * kC
                   + (size_t)(blk >> 3) * (kPasses * kTPB);

    const float t0x = trans[6 * p + 0], t0y = trans[6 * p + 1], t0z = trans[6 * p + 2];
    const float t1x = trans[6 * p + 3], t1y = trans[6 * p + 4], t1z = trans[6 * p + 5];

    volatile __shared__ int s_exit;
    if (threadIdx.x == 0) s_exit = 0;
    __syncthreads();

    float acc = 0.0f;
    for (int s = 0; s < kPasses; ++s) {
        int2 idx = cp[s * kTPB + threadIdx.x];
        acc += eval_collision(p, idx, verts, faces, t0x, t0y, t0z, t1x, t1y, t1z);
        if (__any(acc >= THRESH_F)) {
            // this wave's partial is already >= 2000 => pair provably discarded
            if (lane == 0) s_exit = 1;      // CU-local hint for sibling waves
            break;
        }
        if (s + 1 < kPasses && s_exit) break;  // advisory; benign race
    }

    // wave reduce -> LDS -> one plain store per block
#pragma unroll
    for (int off = 32; off > 0; off >>= 1)
        acc += __shfl_down(acc, off, 64);
    __shared__ float red[kWPB];
    if (lane == 0) red[wid] = acc;
    __syncthreads();
    if (threadIdx.x == 0)
        g_partials[blk] = red[0] + red[1] + red[2] + red[3];
}

// 1 block, 512 threads = 8 waves; wave w reduces pair w's 32 partials.
__global__ void __launch_bounds__(512)
finalize_kernel(float* __restrict__ out) {
    const int wv   = threadIdx.x >> 6;   // pair 0..7
    const int lane = threadIdx.x & 63;
    float s = 0.0f;
    for (int j = lane; j < kBlocksPerPair; j += 64)   // lanes 0..31 load
        s += g_partials[wv + 8 * j];
#pragma unroll
    for (int off = 32; off > 0; off >>= 1)
        s += __shfl_down(s, off, 64);
    __shared__ float pen[kP];
    if (lane == 0) pen[wv] = s;
    __syncthreads();
    if (threadIdx.x == 0) {
        float cnt = 0.0f, vals = 0.0f;
#pragma unroll
        for (int e = 0; e < kP; ++e) {
            float pq = pen[e];
            if (pq < THRESH_F) {             // NaN pen => excluded, matches jax
                cnt += 1.0f;
                vals += 1.0f / (1.0f + expf(-pq / THRESH_F)) - 0.5f;
            }
        }
        float loss = (cnt > 0.0f) ? (vals / fmaxf(cnt, 1.0f)) : 0.0f;
        out[0] = loss * WEIGHT_F;
    }
}

extern "C" void kernel_launch(void* const* d_in, const int* in_sizes, int n_in,
                              void* d_out, int out_size, void* d_ws, size_t ws_size,
                              hipStream_t stream) {
    const float* verts = (const float*)d_in[0];
    const float* trans = (const float*)d_in[1];
    const int*   faces = (const int*)d_in[2];
    const int*   coll  = (const int*)d_in[3];
    (void)d_ws; (void)ws_size; (void)in_sizes; (void)n_in; (void)out_size;
    pen_kernel<<<kNB, kTPB, 0, stream>>>(coll, verts, trans, faces);
    finalize_kernel<<<1, 512, 0, stream>>>((float*)d_out);
}